// Round 4
// baseline (379.798 us; speedup 1.0000x reference)
//
#include <hip/hip_runtime.h>

#define B_ 64
#define H_ 32
#define DN 512
#define DR 64
#define BS 128
#define SB 64
#define MAXKV 4096
#define LOG2E 1.44269504088896340736f
#define SCALE_ (1.0f/24.0f)   // 1/sqrt(576)
#define NEG_INF -1e30f

typedef float    f32x4 __attribute__((ext_vector_type(4)));
typedef _Float16 f16x4 __attribute__((ext_vector_type(4)));

#define MFMA16 __builtin_amdgcn_mfma_f32_16x16x16f16

__device__ __forceinline__ f16x4 cvt4(f32x4 a) {
  f16x4 r;
  r[0] = (_Float16)a[0]; r[1] = (_Float16)a[1];
  r[2] = (_Float16)a[2]; r[3] = (_Float16)a[3];
  return r;
}

// Barrier WITHOUT the compiler's vmcnt(0) drain: LDS ordering only.
// Keeps the cross-sub-block K prefetch loads in flight (T3/T4 pattern).
__device__ __forceinline__ void barrier_nodrain() {
  asm volatile("s_waitcnt lgkmcnt(0)" ::: "memory");
  __builtin_amdgcn_sched_barrier(0);
  __builtin_amdgcn_s_barrier();
  __builtin_amdgcn_sched_barrier(0);
}

// Kernel 1: per (b, chunk) flash-decode partial. 4 waves; per 64-key
// sub-block each wave owns one 16-key S-tile (S^T = K·Q^T, 16x16x16 f16
// MFMA) and a 128-dim slice for PV. Next sub-block's K-nope tile is
// register-prefetched (32 x f32x4) and stays in flight across the
// softmax/PV phases thanks to drain-free barriers.
__global__ __launch_bounds__(256, 2) void mla_chunk(
    const float* __restrict__ qn, const float* __restrict__ qr,
    const float* __restrict__ kvn, const float* __restrict__ kvr,
    const int* __restrict__ btab, const int* __restrict__ kseq,
    _Float16* __restrict__ po, float* __restrict__ ml,
    const int nc, const int chunk)
{
  const int bc = blockIdx.x;
  const int b = bc / nc, c = bc - b * nc;
  const int klen = kseq[b];
  const int kbase = c * chunk;
  if (kbase >= klen) return;
  const int nvalid = min(chunk, klen - kbase);
  const int nsb = (nvalid + SB - 1) / SB;

  const int tid = threadIdx.x;
  const int w = tid >> 6, l = tid & 63, l15 = l & 15, lg = l >> 4;
  const int kd = lg * 4;

  __shared__ _Float16 Vt[DN][SB + 4];       // V^T: [dim][key], 69.6 KB
  __shared__ _Float16 Plds[H_][72];         // P: [head][key-local]
  __shared__ float m_tab[4][H_], l_tab[4][H_];
  __shared__ float Mnew_s[H_], fact_s[H_], Mrun[H_], Lrun[H_];

  if (tid < H_) { Mrun[tid] = NEG_INF; Lrun[tid] = 0.f; }

  f32x4 acc[2][8];
  #pragma unroll
  for (int i = 0; i < 2; ++i)
    #pragma unroll
    for (int j = 0; j < 8; ++j) acc[i][j] = (f32x4){0.f, 0.f, 0.f, 0.f};

  // Q row pointers (L2-resident; re-read per sub-block)
  const float* q0  = qn + ((size_t)b * H_ + l15) * DN + kd;
  const float* q1  = qn + ((size_t)b * H_ + 16 + l15) * DN + kd;
  const float* qr0 = qr + ((size_t)b * H_ + l15) * DR + kd;
  const float* qr1 = qr + ((size_t)b * H_ + 16 + l15) * DR + kd;

  const int klr = w * 16 + l15;             // key-local index in sub-block

  // ---- prologue: register-prefetch K-nope for sb = 0 ----
  f32x4 kp[32];                             // static indexing only
  {
    const int kb  = kbase + w * 16;
    const int blk = btab[b * 32 + (kb >> 7)];
    const int row = (kb & (BS - 1)) + l15;
    const float* knp = kvn + ((size_t)blk * BS + row) * DN + kd;
    #pragma unroll
    for (int i = 0; i < 32; ++i) kp[i] = *(const f32x4*)(knp + i * 16);
  }

  barrier_nodrain();

  for (int sb = 0; sb < nsb; ++sb) {
    const int kb  = kbase + sb * SB + w * 16;
    const int blk = btab[b * 32 + (kb >> 7)];
    const int row = (kb & (BS - 1)) + l15;
    const float* kr_ = kvr + ((size_t)blk * BS + row) * DR + kd;

    // ---- Phase A: S^T tile = K·Q^T over 576 dims; stage V^T in LDS ----
    f32x4 s0 = {0.f,0.f,0.f,0.f}, s1 = {0.f,0.f,0.f,0.f};
    #pragma unroll
    for (int d0 = 0; d0 < 32; ++d0) {
      const int dd = d0 * 16 + kd;
      f16x4 af = cvt4(kp[d0]);
      Vt[dd + 0][klr] = af[0]; Vt[dd + 1][klr] = af[1];
      Vt[dd + 2][klr] = af[2]; Vt[dd + 3][klr] = af[3];
      s0 = MFMA16(af, cvt4(*(const f32x4*)(q0 + d0 * 16)), s0, 0, 0, 0);
      s1 = MFMA16(af, cvt4(*(const f32x4*)(q1 + d0 * 16)), s1, 0, 0, 0);
    }
    #pragma unroll
    for (int d0 = 0; d0 < 4; ++d0) {        // rope dims, loaded inline
      f16x4 af = cvt4(*(const f32x4*)(kr_ + d0 * 16));
      s0 = MFMA16(af, cvt4(*(const f32x4*)(qr0 + d0 * 16)), s0, 0, 0, 0);
      s1 = MFMA16(af, cvt4(*(const f32x4*)(qr1 + d0 * 16)), s1, 0, 0, 0);
    }

    // ---- issue next sub-block's K prefetch (stays in flight thru B-E) ----
    if (sb + 1 < nsb) {
      const int kb2  = kbase + (sb + 1) * SB + w * 16;
      const int blk2 = btab[b * 32 + (kb2 >> 7)];
      const int row2 = (kb2 & (BS - 1)) + l15;
      const float* knp = kvn + ((size_t)blk2 * BS + row2) * DN + kd;
      #pragma unroll
      for (int i = 0; i < 32; ++i) kp[i] = *(const f32x4*)(knp + i * 16);
    }

    // D layout: row(key) = lg*4 + r, col(head) = l15. Scale+mask+max.
    float v0[4], v1[4];
    float mx0 = NEG_INF, mx1 = NEG_INF;
    #pragma unroll
    for (int r = 0; r < 4; ++r) {
      const bool ok = (kb + lg * 4 + r) < klen;
      v0[r] = ok ? s0[r] * SCALE_ : NEG_INF;
      v1[r] = ok ? s1[r] * SCALE_ : NEG_INF;
      mx0 = fmaxf(mx0, v0[r]); mx1 = fmaxf(mx1, v1[r]);
    }
    mx0 = fmaxf(mx0, __shfl_xor(mx0, 16)); mx0 = fmaxf(mx0, __shfl_xor(mx0, 32));
    mx1 = fmaxf(mx1, __shfl_xor(mx1, 16)); mx1 = fmaxf(mx1, __shfl_xor(mx1, 32));
    if (lg == 0) { m_tab[w][l15] = mx0; m_tab[w][16 + l15] = mx1; }
    barrier_nodrain();

    // ---- Phase B: combine running max per head ----
    if (tid < H_) {
      const float mp = Mrun[tid];
      float mn = fmaxf(fmaxf(m_tab[0][tid], m_tab[1][tid]),
                       fmaxf(m_tab[2][tid], m_tab[3][tid]));
      mn = fmaxf(mn, mp);
      Mnew_s[tid] = mn;
      fact_s[tid] = exp2f((mp - mn) * LOG2E);
      Mrun[tid]   = mn;
    }
    barrier_nodrain();

    // ---- Phase C: P = exp(s - M) -> LDS; rescale out-acc ----
    const float mn0 = Mnew_s[l15], mn1 = Mnew_s[16 + l15];
    float p0[4], p1[4];
    float ls0 = 0.f, ls1 = 0.f;
    #pragma unroll
    for (int r = 0; r < 4; ++r) {
      p0[r] = exp2f((v0[r] - mn0) * LOG2E); ls0 += p0[r];
      p1[r] = exp2f((v1[r] - mn1) * LOG2E); ls1 += p1[r];
    }
    ls0 += __shfl_xor(ls0, 16); ls0 += __shfl_xor(ls0, 32);
    ls1 += __shfl_xor(ls1, 16); ls1 += __shfl_xor(ls1, 32);
    if (lg == 0) { l_tab[w][l15] = ls0; l_tab[w][16 + l15] = ls1; }
    f16x4 pk0, pk1;
    #pragma unroll
    for (int r = 0; r < 4; ++r) { pk0[r] = (_Float16)p0[r]; pk1[r] = (_Float16)p1[r]; }
    *(f16x4*)&Plds[l15][w * 16 + kd]      = pk0;
    *(f16x4*)&Plds[16 + l15][w * 16 + kd] = pk1;
    #pragma unroll
    for (int ht = 0; ht < 2; ++ht) {
      #pragma unroll
      for (int r = 0; r < 4; ++r) {
        const float f = fact_s[ht * 16 + lg * 4 + r];
        #pragma unroll
        for (int dt = 0; dt < 8; ++dt) acc[ht][dt][r] *= f;
      }
    }
    barrier_nodrain();

    // ---- Phase D: running denominator ----
    if (tid < H_) {
      Lrun[tid] = Lrun[tid] * fact_s[tid] +
                  (l_tab[0][tid] + l_tab[1][tid]) + (l_tab[2][tid] + l_tab[3][tid]);
    }

    // ---- Phase E: PV. Wave w owns dims [w*128, w*128+128). ----
    #pragma unroll
    for (int ks = 0; ks < 4; ++ks) {
      f16x4 pa0 = *(const f16x4*)&Plds[l15][ks * 16 + kd];
      f16x4 pa1 = *(const f16x4*)&Plds[16 + l15][ks * 16 + kd];
      #pragma unroll
      for (int dt = 0; dt < 8; ++dt) {
        // B-frag: V[key = ks*16 + lg*4 + i][dim = w*128 + dt*16 + l15]
        f16x4 bv = *(const f16x4*)&Vt[w * 128 + dt * 16 + l15][ks * 16 + kd];
        acc[0][dt] = MFMA16(pa0, bv, acc[0][dt], 0, 0, 0);
        acc[1][dt] = MFMA16(pa1, bv, acc[1][dt], 0, 0, 0);
      }
    }
    barrier_nodrain();   // protect Vt/Plds for next sub-block
  }

  // ---- write partials: O (unnormalized, f16), m, l ----
  _Float16* pop = po + ((size_t)(b * nc + c)) * H_ * DN;
  #pragma unroll
  for (int ht = 0; ht < 2; ++ht)
    #pragma unroll
    for (int dt = 0; dt < 8; ++dt)
      #pragma unroll
      for (int r = 0; r < 4; ++r)
        pop[(size_t)(ht * 16 + lg * 4 + r) * DN + w * 128 + dt * 16 + l15] =
            (_Float16)acc[ht][dt][r];
  if (tid < H_) {
    const size_t o = ((size_t)(b * nc + c) * H_ + tid) * 2;
    ml[o] = Mrun[tid]; ml[o + 1] = Lrun[tid];
  }
}

// Kernel 2: merge chunk partials per (b,h).
__global__ __launch_bounds__(256) void mla_reduce(
    const _Float16* __restrict__ po, const float* __restrict__ ml,
    const int* __restrict__ kseq, float* __restrict__ out,
    const int nc, const int chunk)
{
  const int bh = blockIdx.x;
  const int b = bh >> 5, h = bh & 31;
  const int klen = kseq[b];
  const int na = min(nc, (klen + chunk - 1) / chunk);
  const int tid = threadIdx.x;

  float M = NEG_INF;
  for (int c = 0; c < na; ++c)
    M = fmaxf(M, ml[((size_t)(b * nc + c) * H_ + h) * 2]);

  float s0 = 0.f, s1 = 0.f, den = 0.f;
  for (int c = 0; c < na; ++c) {
    const size_t o = ((size_t)(b * nc + c) * H_ + h) * 2;
    const float e = exp2f((ml[o] - M) * LOG2E);
    den += ml[o + 1] * e;
    const _Float16* p = po + ((size_t)(b * nc + c) * H_ + h) * DN;
    s0 += (float)p[tid] * e;
    s1 += (float)p[tid + 256] * e;
  }
  const float inv = 1.f / den;
  float* op = out + ((size_t)b * H_ + h) * DN;
  op[tid]       = s0 * inv;
  op[tid + 256] = s1 * inv;
}

extern "C" void kernel_launch(void* const* d_in, const int* in_sizes, int n_in,
                              void* d_out, int out_size, void* d_ws, size_t ws_size,
                              hipStream_t stream) {
  const float* qn  = (const float*)d_in[0];
  const float* qr  = (const float*)d_in[1];
  const float* kvn = (const float*)d_in[2];
  const float* kvr = (const float*)d_in[3];
  const int*  btab = (const int*)d_in[4];
  const int*  kseq = (const int*)d_in[6];
  float* out = (float*)d_out;

  // workspace-adaptive chunk count: nc chunks of 4096/nc keys
  int nc = 16;
  while (nc > 1 &&
         ((size_t)B_ * nc * H_ * DN * sizeof(_Float16) +
          (size_t)B_ * nc * H_ * 2 * sizeof(float)) > ws_size)
    nc >>= 1;
  const int chunk = MAXKV / nc;

  _Float16* po = (_Float16*)d_ws;                          // [B][nc][H][DN] f16
  float* ml = (float*)(po + (size_t)B_ * nc * H_ * DN);    // [B][nc][H][2]  f32

  mla_chunk<<<B_ * nc, 256, 0, stream>>>(qn, qr, kvn, kvr, btab, kseq,
                                         po, ml, nc, chunk);
  mla_reduce<<<B_ * H_, 256, 0, stream>>>(po, ml, kseq, out, nc, chunk);
}

// Round 5
// 159.141 us; speedup vs baseline: 2.3865x; 2.3865x over previous
//
#include <hip/hip_runtime.h>

#define B_ 64
#define H_ 32
#define DN 512
#define DR 64
#define BS 128
#define TK 32              // keys per tile
#define MAXKV 4096
#define LOG2E 1.44269504088896340736f
#define SCALE_ (1.0f/24.0f)   // 1/sqrt(576)
#define NEG_INF -1e30f

typedef float    f32x4 __attribute__((ext_vector_type(4)));
typedef _Float16 f16x4 __attribute__((ext_vector_type(4)));

#define MFMA16 __builtin_amdgcn_mfma_f32_16x16x16f16

__device__ __forceinline__ f16x4 cvt4(f32x4 a) {
  f16x4 r;
  r[0] = (_Float16)a[0]; r[1] = (_Float16)a[1];
  r[2] = (_Float16)a[2]; r[3] = (_Float16)a[3];
  return r;
}

// LDS-only barrier: drains lgkm, leaves global_load_lds (vmcnt) in flight.
__device__ __forceinline__ void ldsbar() {
  asm volatile("s_waitcnt lgkmcnt(0)" ::: "memory");
  __builtin_amdgcn_sched_barrier(0);
  __builtin_amdgcn_s_barrier();
  __builtin_amdgcn_sched_barrier(0);
}

// Counted wait for the current tile's DMA (18 loads/wave/tile), then barrier.
__device__ __forceinline__ void wait_tile(bool next_in_flight) {
  if (next_in_flight) asm volatile("s_waitcnt vmcnt(18)" ::: "memory");
  else                asm volatile("s_waitcnt vmcnt(0)"  ::: "memory");
  __builtin_amdgcn_sched_barrier(0);
  __builtin_amdgcn_s_barrier();
  __builtin_amdgcn_sched_barrier(0);
}

__device__ __forceinline__ void gl_lds16(const float* g, void* l) {
  __builtin_amdgcn_global_load_lds(
      (const __attribute__((address_space(1))) void*)g,
      (__attribute__((address_space(3))) void*)l, 16, 0, 0);
}

// Stage one 32-key tile (K-nope f32 [32][512] + rope [32][64]) into LDS via
// global_load_lds. LDS dest is linear (base + lane*16); the XOR swizzle
// (slot ^= key&7, 16B slots) is applied on the per-lane GLOBAL source, so
// LDS holds the swizzled layout; reads apply the same XOR (involution).
__device__ __forceinline__ void stage_tile(
    float* kb_lds, float* kr_lds,
    const float* kvn, const float* kvr,
    const size_t blkrow,  // blk*BS + row offset of key 0 of this tile
    const int w, const int lane)
{
  #pragma unroll
  for (int j = 0; j < 16; ++j) {
    const int I  = w * 16 + j;
    const int kl = I >> 1;                    // key-local 0..31
    const int sp = ((I & 1) << 6) + lane;     // physical 16B slot 0..127
    const int s  = sp ^ (kl & 7);             // content slot
    const float* src = kvn + (blkrow + kl) * DN + s * 4;
    gl_lds16(src, (char*)kb_lds + I * 1024);
  }
  #pragma unroll
  for (int j = 0; j < 2; ++j) {
    const int I  = w * 2 + j;
    const int kl = I * 4 + (lane >> 4);       // key-local 0..31
    const int sp = lane & 15;                 // physical slot 0..15
    const int s  = sp ^ (kl & 7);
    const float* src = kvr + (blkrow + kl) * DR + s * 4;
    gl_lds16(src, (char*)kr_lds + I * 1024);
  }
}

// Kernel 1: per (b, chunk) flash-decode partial. 4 waves, 32-key tiles,
// double-buffered f32 K in LDS (DMA-staged), Q in f16 registers.
// S^T: wave (wk,wh) computes [16 keys][16 heads] over 576 dims.
// PV : wave (hv,dv) computes [16 heads][256 dims], V read from K-LDS.
__global__ __launch_bounds__(256, 1) void mla_chunk(
    const float* __restrict__ qn, const float* __restrict__ qr,
    const float* __restrict__ kvn, const float* __restrict__ kvr,
    const int* __restrict__ btab, const int* __restrict__ kseq,
    _Float16* __restrict__ po, float* __restrict__ ml,
    const int nc, const int chunk)
{
  // XCD swizzle: grid is divisible by 8; consecutive bc share an XCD.
  const int raw = blockIdx.x;
  const int bc  = (raw & 7) * ((int)gridDim.x >> 3) + (raw >> 3);
  const int b = bc / nc, c = bc - b * nc;
  const int klen = kseq[b];
  const int kbase = c * chunk;
  if (kbase >= klen) return;
  const int nvalid = min(chunk, klen - kbase);
  const int nsb = (nvalid + TK - 1) / TK;

  const int tid = threadIdx.x;
  const int w = tid >> 6, l = tid & 63, l15 = l & 15, lg = l >> 4;
  const int kd = lg * 4;
  const int wk = w >> 1, wh = w & 1;      // S-tile coords
  const int hv = w >> 1, dv = w & 1;      // PV coords

  __shared__ float KB[2][TK][DN];         // 2 x 64 KB, swizzled
  __shared__ float KR[2][TK][DR];         // 2 x 8 KB, swizzled
  __shared__ _Float16 Plds[H_][40];       // P[head][key], padded
  __shared__ float m_tab[2][H_], l_tab[2][H_];
  __shared__ float Mnew_s[H_], fact_s[H_], Mrun[H_], Lrun[H_];

  if (tid < H_) { Mrun[tid] = NEG_INF; Lrun[tid] = 0.f; }

  f32x4 acc[16];
  #pragma unroll
  for (int i = 0; i < 16; ++i) acc[i] = (f32x4){0.f, 0.f, 0.f, 0.f};

  // ---- Q fragments in f16 registers (once per block) ----
  // B-frag: col = l15 -> head wh*16+l15, k = kd+i -> dim d0*16+kd+i.
  f16x4 Qf[36];
  {
    const float* qn_ = qn + ((size_t)b * H_ + wh * 16 + l15) * DN + kd;
    const float* qr_ = qr + ((size_t)b * H_ + wh * 16 + l15) * DR + kd;
    #pragma unroll
    for (int i = 0; i < 32; ++i) Qf[i] = cvt4(*(const f32x4*)(qn_ + i * 16));
    #pragma unroll
    for (int i = 0; i < 4; ++i) Qf[32 + i] = cvt4(*(const f32x4*)(qr_ + i * 16));
  }

  // ---- prologue: stage tiles 0 and 1 ----
  {
    const int kb0 = kbase;
    const size_t br0 = (size_t)btab[b * 32 + (kb0 >> 7)] * BS + (kb0 & (BS - 1));
    stage_tile(&KB[0][0][0], &KR[0][0][0], kvn, kvr, br0, w, l);
    if (nsb > 1) {
      const int kb1 = kbase + TK;
      const size_t br1 = (size_t)btab[b * 32 + (kb1 >> 7)] * BS + (kb1 & (BS - 1));
      stage_tile(&KB[1][0][0], &KR[1][0][0], kvn, kvr, br1, w, l);
    }
  }

  for (int t = 0; t < nsb; ++t) {
    const int buf = t & 1;
    wait_tile(t + 1 < nsb);     // tile t arrived (t+1 may stay in flight)

    // ---- Phase A: S^T = K . Q^T (from LDS, swizzled reads) ----
    const int k_ = wk * 16 + l15;                 // A-frag row: key-local
    const char* kA = (const char*)&KB[buf][0][0] + k_ * 2048;
    const char* rA = (const char*)&KR[buf][0][0] + k_ * 256;
    f32x4 s0 = {0.f, 0.f, 0.f, 0.f};
    #pragma unroll
    for (int d0 = 0; d0 < 32; ++d0) {
      f32x4 kv4 = *(const f32x4*)(kA + ((((d0 << 2) + lg) ^ (k_ & 7)) << 4));
      s0 = MFMA16(cvt4(kv4), Qf[d0], s0, 0, 0, 0);
    }
    #pragma unroll
    for (int d0 = 0; d0 < 4; ++d0) {
      f32x4 kv4 = *(const f32x4*)(rA + ((((d0 << 2) + lg) ^ (k_ & 7)) << 4));
      s0 = MFMA16(cvt4(kv4), Qf[32 + d0], s0, 0, 0, 0);
    }

    // ---- mask + per-wave max (16 keys per head) ----
    const int kb = kbase + t * TK;
    float v0[4];
    float mx = NEG_INF;
    #pragma unroll
    for (int r = 0; r < 4; ++r) {
      const bool ok = (kb + wk * 16 + kd + r) < klen;
      v0[r] = ok ? s0[r] * SCALE_ : NEG_INF;
      mx = fmaxf(mx, v0[r]);
    }
    mx = fmaxf(mx, __shfl_xor(mx, 16));
    mx = fmaxf(mx, __shfl_xor(mx, 32));
    if (lg == 0) m_tab[wk][wh * 16 + l15] = mx;
    ldsbar();

    // ---- Phase B: combine running max per head ----
    if (tid < H_) {
      const float mp = Mrun[tid];
      float mn = fmaxf(fmaxf(m_tab[0][tid], m_tab[1][tid]), mp);
      Mnew_s[tid] = mn;
      fact_s[tid] = exp2f((mp - mn) * LOG2E);
      Mrun[tid]   = mn;
    }
    ldsbar();

    // ---- Phase C: P = exp(s-M) -> LDS; rescale acc ----
    const float mnH = Mnew_s[wh * 16 + l15];
    float p0[4];
    float ls = 0.f;
    #pragma unroll
    for (int r = 0; r < 4; ++r) {
      p0[r] = exp2f((v0[r] - mnH) * LOG2E);
      ls += p0[r];
    }
    ls += __shfl_xor(ls, 16);
    ls += __shfl_xor(ls, 32);
    if (lg == 0) l_tab[wk][wh * 16 + l15] = ls;
    f16x4 pk;
    #pragma unroll
    for (int r = 0; r < 4; ++r) pk[r] = (_Float16)p0[r];
    *(f16x4*)&Plds[wh * 16 + l15][wk * 16 + kd] = pk;
    #pragma unroll
    for (int r = 0; r < 4; ++r) {
      const float f = fact_s[hv * 16 + kd + r];
      #pragma unroll
      for (int dt = 0; dt < 16; ++dt) acc[dt][r] *= f;
    }
    ldsbar();

    // ---- Phase D: running denominator ----
    if (tid < H_)
      Lrun[tid] = Lrun[tid] * fact_s[tid] + l_tab[0][tid] + l_tab[1][tid];

    // ---- Phase E: PV from K-LDS (V = K-nope) ----
    #pragma unroll
    for (int ks = 0; ks < 2; ++ks) {
      f16x4 pa = *(const f16x4*)&Plds[hv * 16 + l15][ks * 16 + kd];
      #pragma unroll
      for (int dt = 0; dt < 16; ++dt) {
        const int cc = dv * 256 + dt * 16 + l15;   // dim column
        float b4[4];
        #pragma unroll
        for (int i = 0; i < 4; ++i) {
          const int k2 = ks * 16 + kd + i;         // key (k-dim)
          b4[i] = *(const float*)((const char*)&KB[buf][0][0] + k2 * 2048
                    + ((((cc >> 2) ^ (k2 & 7)) << 4) + ((cc & 3) << 2)));
        }
        f16x4 bv;
        bv[0] = (_Float16)b4[0]; bv[1] = (_Float16)b4[1];
        bv[2] = (_Float16)b4[2]; bv[3] = (_Float16)b4[3];
        acc[dt] = MFMA16(pa, bv, acc[dt], 0, 0, 0);
      }
    }
    ldsbar();   // all reads of buf done block-wide

    // ---- stage tile t+2 into this buffer (stays in flight) ----
    if (t + 2 < nsb) {
      const int kb2 = kbase + (t + 2) * TK;
      const size_t br2 = (size_t)btab[b * 32 + (kb2 >> 7)] * BS + (kb2 & (BS - 1));
      stage_tile(&KB[buf][0][0], &KR[buf][0][0], kvn, kvr, br2, w, l);
    }
  }

  // ---- write partials: O (unnormalized, f16), m, l ----
  _Float16* pop = po + (size_t)(b * nc + c) * H_ * DN;
  #pragma unroll
  for (int dt = 0; dt < 16; ++dt)
    #pragma unroll
    for (int r = 0; r < 4; ++r)
      pop[(size_t)(hv * 16 + kd + r) * DN + dv * 256 + dt * 16 + l15] =
          (_Float16)acc[dt][r];
  if (tid < H_) {
    const size_t o = ((size_t)(b * nc + c) * H_ + tid) * 2;
    ml[o] = Mrun[tid]; ml[o + 1] = Lrun[tid];
  }
}

// Kernel 2: merge chunk partials per (b,h).
__global__ __launch_bounds__(256) void mla_reduce(
    const _Float16* __restrict__ po, const float* __restrict__ ml,
    const int* __restrict__ kseq, float* __restrict__ out,
    const int nc, const int chunk)
{
  const int bh = blockIdx.x;
  const int b = bh >> 5, h = bh & 31;
  const int klen = kseq[b];
  const int na = min(nc, (klen + chunk - 1) / chunk);
  const int tid = threadIdx.x;

  float M = NEG_INF;
  for (int c = 0; c < na; ++c)
    M = fmaxf(M, ml[((size_t)(b * nc + c) * H_ + h) * 2]);

  float s0 = 0.f, s1 = 0.f, den = 0.f;
  for (int c = 0; c < na; ++c) {
    const size_t o = ((size_t)(b * nc + c) * H_ + h) * 2;
    const float e = exp2f((ml[o] - M) * LOG2E);
    den += ml[o + 1] * e;
    const _Float16* p = po + ((size_t)(b * nc + c) * H_ + h) * DN;
    s0 += (float)p[tid] * e;
    s1 += (float)p[tid + 256] * e;
  }
  const float inv = 1.f / den;
  float* op = out + ((size_t)b * H_ + h) * DN;
  op[tid]       = s0 * inv;
  op[tid + 256] = s1 * inv;
}

extern "C" void kernel_launch(void* const* d_in, const int* in_sizes, int n_in,
                              void* d_out, int out_size, void* d_ws, size_t ws_size,
                              hipStream_t stream) {
  const float* qn  = (const float*)d_in[0];
  const float* qr  = (const float*)d_in[1];
  const float* kvn = (const float*)d_in[2];
  const float* kvr = (const float*)d_in[3];
  const int*  btab = (const int*)d_in[4];
  const int*  kseq = (const int*)d_in[6];
  float* out = (float*)d_out;

  // workspace-adaptive chunk count: nc chunks of 4096/nc keys
  int nc = 16;
  while (nc > 1 &&
         ((size_t)B_ * nc * H_ * DN * sizeof(_Float16) +
          (size_t)B_ * nc * H_ * 2 * sizeof(float)) > ws_size)
    nc >>= 1;
  const int chunk = MAXKV / nc;

  _Float16* po = (_Float16*)d_ws;                          // [B][nc][H][DN] f16
  float* ml = (float*)(po + (size_t)B_ * nc * H_ * DN);    // [B][nc][H][2]  f32

  mla_chunk<<<B_ * nc, 256, 0, stream>>>(qn, qr, kvn, kvr, btab, kseq,
                                         po, ml, nc, chunk);
  mla_reduce<<<B_ * H_, 256, 0, stream>>>(po, ml, kseq, out, nc, chunk);
}